// Round 1
// baseline (649.430 us; speedup 1.0000x reference)
//
#include <hip/hip_runtime.h>
#include <hip/hip_bf16.h>

typedef __bf16 bf16;
typedef __bf16 bf16x4 __attribute__((ext_vector_type(4)));
typedef __bf16 bf16x8 __attribute__((ext_vector_type(8)));
typedef float f32x4 __attribute__((ext_vector_type(4)));

constexpr int T = 2048;      // tokens (B*S)
constexpr int HD = 1024;     // hidden
constexpr int NE = 8;        // experts
constexpr int IEXP = 2816;   // expert intermediate
constexpr int ISH = 1408;    // shared intermediate
constexpr int NSLOT = T * 2; // routed (token,slot) rows

typedef __attribute__((address_space(1))) void gvoid;
typedef __attribute__((address_space(3))) void svoid;

__device__ __forceinline__ void gload_lds16(const void* g, void* l) {
  __builtin_amdgcn_global_load_lds((gvoid*)g, (svoid*)l, 16, 0, 0);
}

// ---------------- x fp32 -> bf16 ----------------
__global__ __launch_bounds__(256) void k_convert_x(const float* __restrict__ x,
                                                   bf16* __restrict__ xb, int n4) {
  int i = blockIdx.x * blockDim.x + threadIdx.x;
  if (i >= n4) return;
  float4 v = reinterpret_cast<const float4*>(x)[i];
  bf16x4 o; o[0] = (bf16)v.x; o[1] = (bf16)v.y; o[2] = (bf16)v.z; o[3] = (bf16)v.w;
  reinterpret_cast<bf16x4*>(xb)[i] = o;
}

// ---------------- [b][K][N] f32 -> [b][N][K] bf16 (all dims %32==0) ----------------
__global__ __launch_bounds__(256) void k_transpose(const float* __restrict__ in,
                                                   bf16* __restrict__ out,
                                                   int Kd, int Nd) {
  __shared__ float tile[32][33];
  int b = blockIdx.z;
  int n0 = blockIdx.x * 32, k0 = blockIdx.y * 32;
  const float* src = in + (size_t)b * Kd * Nd;
  bf16* dst = out + (size_t)b * Kd * Nd;
  int t = threadIdx.x;
  int r = t >> 3, c4 = (t & 7) * 4;
  float4 v = *reinterpret_cast<const float4*>(src + (size_t)(k0 + r) * Nd + n0 + c4);
  tile[r][c4 + 0] = v.x; tile[r][c4 + 1] = v.y; tile[r][c4 + 2] = v.z; tile[r][c4 + 3] = v.w;
  __syncthreads();
  bf16x4 o;
  o[0] = (bf16)tile[c4 + 0][r]; o[1] = (bf16)tile[c4 + 1][r];
  o[2] = (bf16)tile[c4 + 2][r]; o[3] = (bf16)tile[c4 + 3][r];
  *reinterpret_cast<bf16x4*>(dst + (size_t)(n0 + r) * Kd + k0 + c4) = o;
}

// ---------------- router: logits, top-2, softmax, counts ----------------
__global__ __launch_bounds__(64) void k_router(const float* __restrict__ x,
                                               const float* __restrict__ gw,
                                               int* __restrict__ topi,
                                               float* __restrict__ topp,
                                               int* __restrict__ counts) {
  int t = blockIdx.x;
  int l = threadIdx.x;
  float acc[NE];
  #pragma unroll
  for (int e = 0; e < NE; ++e) acc[e] = 0.f;
  const float* xr = x + (size_t)t * HD;
  for (int i = 0; i < HD / 64; ++i) {
    int h = i * 64 + l;
    float xv = xr[h];
    const float* g = gw + (size_t)h * NE;
    #pragma unroll
    for (int e = 0; e < NE; ++e) acc[e] += xv * g[e];
  }
  #pragma unroll
  for (int e = 0; e < NE; ++e) {
    float v = acc[e];
    #pragma unroll
    for (int s = 32; s; s >>= 1) v += __shfl_xor(v, s);
    acc[e] = v;
  }
  if (l == 0) {
    int i0 = 0; float v0 = acc[0];
    #pragma unroll
    for (int e = 1; e < NE; ++e) if (acc[e] > v0) { v0 = acc[e]; i0 = e; }
    int i1 = -1; float v1 = -1e30f;
    #pragma unroll
    for (int e = 0; e < NE; ++e) if (e != i0 && acc[e] > v1) { v1 = acc[e]; i1 = e; }
    float e1 = expf(v1 - v0);
    float den = 1.f + e1;
    topi[t * 2] = i0; topi[t * 2 + 1] = i1;
    topp[t * 2] = 1.f / den; topp[t * 2 + 1] = e1 / den;
    atomicAdd(&counts[i0], 1);
    atomicAdd(&counts[i1], 1);
  }
}

// ---------------- scan of counts + cursor init ----------------
__global__ void k_scan(const int* __restrict__ counts, int* __restrict__ offs,
                       int* __restrict__ cursor, int* __restrict__ soffs) {
  if (threadIdx.x == 0 && blockIdx.x == 0) {
    int s = 0; offs[0] = 0;
    for (int e = 0; e < NE; ++e) { s += counts[e]; offs[e + 1] = s; cursor[e] = 0; }
    soffs[0] = 0; soffs[1] = T;
  }
}

// ---------------- scatter tokens into per-expert segments ----------------
__global__ __launch_bounds__(64) void k_scatter(const int* __restrict__ topi,
                                                const float* __restrict__ topp,
                                                const int* __restrict__ offs,
                                                int* __restrict__ cursor,
                                                int* __restrict__ rowmap,
                                                float* __restrict__ rowp,
                                                int* __restrict__ slotOf) {
  int t = blockIdx.x * blockDim.x + threadIdx.x;
  if (t >= T) return;
  #pragma unroll
  for (int s = 0; s < 2; ++s) {
    int e = topi[t * 2 + s];
    int pos = offs[e] + atomicAdd(&cursor[e], 1);
    rowmap[pos] = t;
    rowp[pos] = topp[t * 2 + s];
    slotOf[t * 2 + s] = pos;
  }
}

// ---------------- fused gate+up GEMM + SiLU*up epilogue ----------------
// BM=128, BN=64, BK=32, 4 waves (2x2), wave tile 64x32, two B matrices.
__global__ __launch_bounds__(256) void k_gateup(
    const bf16* __restrict__ A, const int* __restrict__ rowmap,
    const int* __restrict__ offs, const bf16* __restrict__ Bg,
    const bf16* __restrict__ Bu, bf16* __restrict__ outp, int Nd, int Kd) {
  __shared__ alignas(16) bf16 As[128 * 32];
  __shared__ alignas(16) bf16 Bgs[64 * 32];
  __shared__ alignas(16) bf16 Bus[64 * 32];
  const int z = blockIdx.z;
  const int r0 = offs[z], r1 = offs[z + 1];
  const int mbase = r0 + blockIdx.y * 128;
  if (mbase >= r1) return;
  const int n0 = blockIdx.x * 64;
  const int tid = threadIdx.x, wid = tid >> 6, lane = tid & 63;

  const bf16 *aSrc0, *aSrc1;
  {
    int rl0 = wid * 32 + (lane >> 2);
    int g0 = mbase + rl0;      if (g0 >= r1) g0 = r1 - 1;
    int g1 = mbase + rl0 + 16; if (g1 >= r1) g1 = r1 - 1;
    int s0 = rowmap ? rowmap[g0] : g0;
    int s1 = rowmap ? rowmap[g1] : g1;
    aSrc0 = A + (size_t)s0 * Kd + (lane & 3) * 8;
    aSrc1 = A + (size_t)s1 * Kd + (lane & 3) * 8;
  }
  const size_t bstride = (size_t)Nd * Kd;
  const size_t brow = (size_t)(n0 + wid * 16 + (lane >> 2)) * Kd + (lane & 3) * 8;
  const bf16* bgSrc = Bg + (size_t)z * bstride + brow;
  const bf16* buSrc = Bu + (size_t)z * bstride + brow;
  bf16* aDst0 = &As[(wid * 32) * 32];
  bf16* aDst1 = &As[(wid * 32 + 16) * 32];
  bf16* bgDst = &Bgs[(wid * 16) * 32];
  bf16* buDst = &Bus[(wid * 16) * 32];

  f32x4 zz = {0.f, 0.f, 0.f, 0.f};
  f32x4 accg[4][2], accu[4][2];
  #pragma unroll
  for (int m = 0; m < 4; ++m)
    #pragma unroll
    for (int n = 0; n < 2; ++n) { accg[m][n] = zz; accu[m][n] = zz; }

  const int wr = wid >> 1, wc = wid & 1;
  const int frow = lane & 15, fk = (lane >> 4) * 8;

  for (int k0 = 0; k0 < Kd; k0 += 32) {
    gload_lds16(aSrc0 + k0, aDst0);
    gload_lds16(aSrc1 + k0, aDst1);
    gload_lds16(bgSrc + k0, bgDst);
    gload_lds16(buSrc + k0, buDst);
    __syncthreads();
    bf16x8 af[4], bgf[2], buf2[2];
    #pragma unroll
    for (int m = 0; m < 4; ++m)
      af[m] = *reinterpret_cast<const bf16x8*>(&As[(wr * 64 + m * 16 + frow) * 32 + fk]);
    #pragma unroll
    for (int n = 0; n < 2; ++n) {
      bgf[n]  = *reinterpret_cast<const bf16x8*>(&Bgs[(wc * 32 + n * 16 + frow) * 32 + fk]);
      buf2[n] = *reinterpret_cast<const bf16x8*>(&Bus[(wc * 32 + n * 16 + frow) * 32 + fk]);
    }
    #pragma unroll
    for (int m = 0; m < 4; ++m)
      #pragma unroll
      for (int n = 0; n < 2; ++n) {
        accg[m][n] = __builtin_amdgcn_mfma_f32_16x16x32_bf16(af[m], bgf[n],  accg[m][n], 0, 0, 0);
        accu[m][n] = __builtin_amdgcn_mfma_f32_16x16x32_bf16(af[m], buf2[n], accu[m][n], 0, 0, 0);
      }
    __syncthreads();
  }

  #pragma unroll
  for (int m = 0; m < 4; ++m)
    #pragma unroll
    for (int n = 0; n < 2; ++n)
      #pragma unroll
      for (int j = 0; j < 4; ++j) {
        int r = mbase + wr * 64 + m * 16 + (lane >> 4) * 4 + j;
        if (r < r1) {
          int c = n0 + wc * 32 + n * 16 + (lane & 15);
          float g = accg[m][n][j], u = accu[m][n][j];
          float sv = g / (1.f + __expf(-g));
          outp[(size_t)r * Nd + c] = (bf16)(sv * u);
        }
      }
}

// ---------------- down GEMM, optional per-row prob scale, f32 out ----------------
// BM=128, BN=128, BK=32, 4 waves (2x2), wave tile 64x64.
__global__ __launch_bounds__(256) void k_down(
    const bf16* __restrict__ A, const float* __restrict__ rowp,
    const int* __restrict__ offs, const bf16* __restrict__ Bt,
    float* __restrict__ outp, int Nd, int Kd) {
  __shared__ alignas(16) bf16 As[128 * 32];
  __shared__ alignas(16) bf16 Bs[128 * 32];
  const int z = blockIdx.z;
  const int r0 = offs[z], r1 = offs[z + 1];
  const int mbase = r0 + blockIdx.y * 128;
  if (mbase >= r1) return;
  const int n0 = blockIdx.x * 128;
  const int tid = threadIdx.x, wid = tid >> 6, lane = tid & 63;

  const bf16 *aSrc0, *aSrc1;
  {
    int rl0 = wid * 32 + (lane >> 2);
    int g0 = mbase + rl0;      if (g0 >= r1) g0 = r1 - 1;
    int g1 = mbase + rl0 + 16; if (g1 >= r1) g1 = r1 - 1;
    aSrc0 = A + (size_t)g0 * Kd + (lane & 3) * 8;
    aSrc1 = A + (size_t)g1 * Kd + (lane & 3) * 8;
  }
  const bf16* bSrc0 = Bt + (size_t)z * Nd * Kd +
                      (size_t)(n0 + wid * 32 + (lane >> 2)) * Kd + (lane & 3) * 8;
  const bf16* bSrc1 = bSrc0 + (size_t)16 * Kd;
  bf16* aDst0 = &As[(wid * 32) * 32];
  bf16* aDst1 = &As[(wid * 32 + 16) * 32];
  bf16* bDst0 = &Bs[(wid * 32) * 32];
  bf16* bDst1 = &Bs[(wid * 32 + 16) * 32];

  f32x4 zz = {0.f, 0.f, 0.f, 0.f};
  f32x4 acc[4][4];
  #pragma unroll
  for (int m = 0; m < 4; ++m)
    #pragma unroll
    for (int n = 0; n < 4; ++n) acc[m][n] = zz;

  const int wr = wid >> 1, wc = wid & 1;
  const int frow = lane & 15, fk = (lane >> 4) * 8;

  for (int k0 = 0; k0 < Kd; k0 += 32) {
    gload_lds16(aSrc0 + k0, aDst0);
    gload_lds16(aSrc1 + k0, aDst1);
    gload_lds16(bSrc0 + k0, bDst0);
    gload_lds16(bSrc1 + k0, bDst1);
    __syncthreads();
    bf16x8 af[4], bfr[4];
    #pragma unroll
    for (int m = 0; m < 4; ++m)
      af[m] = *reinterpret_cast<const bf16x8*>(&As[(wr * 64 + m * 16 + frow) * 32 + fk]);
    #pragma unroll
    for (int n = 0; n < 4; ++n)
      bfr[n] = *reinterpret_cast<const bf16x8*>(&Bs[(wc * 64 + n * 16 + frow) * 32 + fk]);
    #pragma unroll
    for (int m = 0; m < 4; ++m)
      #pragma unroll
      for (int n = 0; n < 4; ++n)
        acc[m][n] = __builtin_amdgcn_mfma_f32_16x16x32_bf16(af[m], bfr[n], acc[m][n], 0, 0, 0);
    __syncthreads();
  }

  #pragma unroll
  for (int m = 0; m < 4; ++m)
    #pragma unroll
    for (int j = 0; j < 4; ++j) {
      int r = mbase + wr * 64 + m * 16 + (lane >> 4) * 4 + j;
      if (r < r1) {
        float sc = rowp ? rowp[r] : 1.f;
        #pragma unroll
        for (int n = 0; n < 4; ++n) {
          int c = n0 + wc * 64 + n * 16 + (lane & 15);
          outp[(size_t)r * Nd + c] = sc * acc[m][n][j];
        }
      }
    }
}

// ---------------- final combine: two expert slots + shared ----------------
__global__ __launch_bounds__(256) void k_combine(const float* __restrict__ dout,
                                                 const float* __restrict__ sdown,
                                                 const int* __restrict__ slotOf,
                                                 float* __restrict__ outp) {
  int i = blockIdx.x * blockDim.x + threadIdx.x;  // over T*HD/4
  if (i >= T * HD / 4) return;
  int t = i >> 8;            // (i*4)/1024
  int off = (i & 255) * 4;
  int s0 = slotOf[t * 2], s1 = slotOf[t * 2 + 1];
  float4 a = *reinterpret_cast<const float4*>(dout + (size_t)s0 * HD + off);
  float4 b = *reinterpret_cast<const float4*>(dout + (size_t)s1 * HD + off);
  float4 c = *reinterpret_cast<const float4*>(sdown + (size_t)i * 4);
  float4 o;
  o.x = a.x + b.x + c.x; o.y = a.y + b.y + c.y;
  o.z = a.z + b.z + c.z; o.w = a.w + b.w + c.w;
  *reinterpret_cast<float4*>(outp + (size_t)i * 4) = o;
}

static inline size_t algn(size_t x) { return (x + 255) & ~(size_t)255; }

extern "C" void kernel_launch(void* const* d_in, const int* in_sizes, int n_in,
                              void* d_out, int out_size, void* d_ws, size_t ws_size,
                              hipStream_t stream) {
  const float* x  = (const float*)d_in[0];
  const float* gw = (const float*)d_in[1];
  const float* Wg = (const float*)d_in[2];
  const float* Wu = (const float*)d_in[3];
  const float* Wd = (const float*)d_in[4];
  const float* Sg = (const float*)d_in[5];
  const float* Su = (const float*)d_in[6];
  const float* Sd = (const float*)d_in[7];
  float* out = (float*)d_out;

  char* p = (char*)d_ws;
  auto carve = [&](size_t bytes) -> char* { char* r = p; p += algn(bytes); return r; };
  bf16* xb   = (bf16*)carve((size_t)T * HD * 2);
  bf16* WgT  = (bf16*)carve((size_t)NE * IEXP * HD * 2);
  bf16* WuT  = (bf16*)carve((size_t)NE * IEXP * HD * 2);
  bf16* WdT  = (bf16*)carve((size_t)NE * HD * IEXP * 2);
  bf16* SgT  = (bf16*)carve((size_t)ISH * HD * 2);
  bf16* SuT  = (bf16*)carve((size_t)ISH * HD * 2);
  bf16* SdT  = (bf16*)carve((size_t)HD * ISH * 2);
  bf16* act  = (bf16*)carve((size_t)NSLOT * IEXP * 2);
  bf16* sact = (bf16*)carve((size_t)T * ISH * 2);
  float* dout  = (float*)carve((size_t)NSLOT * HD * 4);
  float* sdown = (float*)carve((size_t)T * HD * 4);
  int*   topi   = (int*)carve(T * 2 * 4);
  float* topp   = (float*)carve(T * 2 * 4);
  int*   rowmap = (int*)carve(NSLOT * 4);
  float* rowp   = (float*)carve(NSLOT * 4);
  int*   slotOf = (int*)carve(T * 2 * 4);
  int*   counts = (int*)carve(NE * 4);
  int*   offs   = (int*)carve((NE + 1) * 4);
  int*   cursor = (int*)carve(NE * 4);
  int*   soffs  = (int*)carve(2 * 4);

  hipMemsetAsync(counts, 0, NE * sizeof(int), stream);

  k_convert_x<<<T * HD / 4 / 256, 256, 0, stream>>>(x, xb, T * HD / 4);

  k_transpose<<<dim3(IEXP / 32, HD / 32, NE), 256, 0, stream>>>(Wg, WgT, HD, IEXP);
  k_transpose<<<dim3(IEXP / 32, HD / 32, NE), 256, 0, stream>>>(Wu, WuT, HD, IEXP);
  k_transpose<<<dim3(HD / 32, IEXP / 32, NE), 256, 0, stream>>>(Wd, WdT, IEXP, HD);
  k_transpose<<<dim3(ISH / 32, HD / 32, 1), 256, 0, stream>>>(Sg, SgT, HD, ISH);
  k_transpose<<<dim3(ISH / 32, HD / 32, 1), 256, 0, stream>>>(Su, SuT, HD, ISH);
  k_transpose<<<dim3(HD / 32, ISH / 32, 1), 256, 0, stream>>>(Sd, SdT, ISH, HD);

  k_router<<<T, 64, 0, stream>>>(x, gw, topi, topp, counts);
  k_scan<<<1, 64, 0, stream>>>(counts, offs, cursor, soffs);
  k_scatter<<<T / 64, 64, 0, stream>>>(topi, topp, offs, cursor, rowmap, rowp, slotOf);

  // expert gate+up (rows gathered via rowmap), worst-case 32 M-tiles
  k_gateup<<<dim3(IEXP / 64, 32, NE), 256, 0, stream>>>(xb, rowmap, offs, WgT, WuT,
                                                        act, IEXP, HD);
  // shared gate+up over all tokens
  k_gateup<<<dim3(ISH / 64, T / 128, 1), 256, 0, stream>>>(xb, nullptr, soffs, SgT, SuT,
                                                           sact, ISH, HD);
  // expert down (prob-scaled)
  k_down<<<dim3(HD / 128, 32, NE), 256, 0, stream>>>(act, rowp, offs, WdT, dout, HD, IEXP);
  // shared down
  k_down<<<dim3(HD / 128, T / 128, 1), 256, 0, stream>>>(sact, nullptr, soffs, SdT,
                                                         sdown, HD, ISH);

  k_combine<<<T * HD / 4 / 256, 256, 0, stream>>>(dout, sdown, slotOf, out);

  (void)in_sizes; (void)n_in; (void)out_size; (void)ws_size;
}

// Round 5
// 560.146 us; speedup vs baseline: 1.1594x; 1.1594x over previous
//
#include <hip/hip_runtime.h>
#include <hip/hip_bf16.h>

typedef __bf16 bf16;
typedef __bf16 bf16x4 __attribute__((ext_vector_type(4)));
typedef __bf16 bf16x8 __attribute__((ext_vector_type(8)));
typedef float f32x4 __attribute__((ext_vector_type(4)));

constexpr int T = 2048;      // tokens (B*S)
constexpr int HD = 1024;     // hidden
constexpr int NE = 8;        // experts
constexpr int IEXP = 2816;   // expert intermediate
constexpr int ISH = 1408;    // shared intermediate
constexpr int NSLOT = T * 2; // routed (token,slot) rows

typedef __attribute__((address_space(1))) void gvoid;
typedef __attribute__((address_space(3))) void svoid;

__device__ __forceinline__ void gload_lds16(const void* g, void* l) {
  __builtin_amdgcn_global_load_lds((gvoid*)g, (svoid*)l, 16, 0, 0);
}

// ---------------- x fp32 -> bf16 ----------------
__global__ __launch_bounds__(256) void k_convert_x(const float* __restrict__ x,
                                                   bf16* __restrict__ xb, int n4) {
  int i = blockIdx.x * blockDim.x + threadIdx.x;
  if (i >= n4) return;
  float4 v = reinterpret_cast<const float4*>(x)[i];
  bf16x4 o; o[0] = (bf16)v.x; o[1] = (bf16)v.y; o[2] = (bf16)v.z; o[3] = (bf16)v.w;
  reinterpret_cast<bf16x4*>(xb)[i] = o;
}

// ------- [b][K][N] f32 -> [b][N][K] bf16, 64x64 tiles, bf16x8 writes -------
__global__ __launch_bounds__(256) void k_transpose64(const float* __restrict__ in,
                                                     bf16* __restrict__ out,
                                                     int Kd, int Nd) {
  __shared__ float tile[64][65];
  const int b = blockIdx.z;
  const int n0 = blockIdx.x * 64, k0 = blockIdx.y * 64;
  const float* src = in + (size_t)b * Kd * Nd;
  bf16* dst = out + (size_t)b * Kd * Nd;
  const int t = threadIdx.x;
  {
    const int r = t >> 4, c = (t & 15) * 4;
    #pragma unroll
    for (int p = 0; p < 4; ++p) {
      float4 v = *reinterpret_cast<const float4*>(src + (size_t)(k0 + p * 16 + r) * Nd + n0 + c);
      tile[p * 16 + r][c + 0] = v.x; tile[p * 16 + r][c + 1] = v.y;
      tile[p * 16 + r][c + 2] = v.z; tile[p * 16 + r][c + 3] = v.w;
    }
  }
  __syncthreads();
  {
    const int kc = (t & 7) * 8;
    #pragma unroll
    for (int p = 0; p < 2; ++p) {
      const int nr = p * 32 + (t >> 3);
      bf16x8 o;
      #pragma unroll
      for (int j = 0; j < 8; ++j) o[j] = (bf16)tile[kc + j][nr];
      *reinterpret_cast<bf16x8*>(dst + (size_t)(n0 + nr) * Kd + k0 + kc) = o;
    }
  }
}

// ---------------- router: logits, top-2, softmax, counts ----------------
__global__ __launch_bounds__(64) void k_router(const float* __restrict__ x,
                                               const float* __restrict__ gw,
                                               int* __restrict__ topi,
                                               float* __restrict__ topp,
                                               int* __restrict__ counts) {
  int t = blockIdx.x;
  int l = threadIdx.x;
  float acc[NE];
  #pragma unroll
  for (int e = 0; e < NE; ++e) acc[e] = 0.f;
  const float* xr = x + (size_t)t * HD;
  for (int i = 0; i < HD / 64; ++i) {
    int h = i * 64 + l;
    float xv = xr[h];
    const float* g = gw + (size_t)h * NE;
    #pragma unroll
    for (int e = 0; e < NE; ++e) acc[e] += xv * g[e];
  }
  #pragma unroll
  for (int e = 0; e < NE; ++e) {
    float v = acc[e];
    #pragma unroll
    for (int s = 32; s; s >>= 1) v += __shfl_xor(v, s);
    acc[e] = v;
  }
  if (l == 0) {
    int i0 = 0; float v0 = acc[0];
    #pragma unroll
    for (int e = 1; e < NE; ++e) if (acc[e] > v0) { v0 = acc[e]; i0 = e; }
    int i1 = -1; float v1 = -1e30f;
    #pragma unroll
    for (int e = 0; e < NE; ++e) if (e != i0 && acc[e] > v1) { v1 = acc[e]; i1 = e; }
    float e1 = expf(v1 - v0);
    float den = 1.f + e1;
    topi[t * 2] = i0; topi[t * 2 + 1] = i1;
    topp[t * 2] = 1.f / den; topp[t * 2 + 1] = e1 / den;
    atomicAdd(&counts[i0], 1);
    atomicAdd(&counts[i1], 1);
  }
}

// ---------------- scan of counts + cursor init ----------------
__global__ void k_scan(const int* __restrict__ counts, int* __restrict__ offs,
                       int* __restrict__ cursor, int* __restrict__ soffs) {
  if (threadIdx.x == 0 && blockIdx.x == 0) {
    int s = 0; offs[0] = 0;
    for (int e = 0; e < NE; ++e) { s += counts[e]; offs[e + 1] = s; cursor[e] = 0; }
    soffs[0] = 0; soffs[1] = T;
  }
}

// ---------------- scatter tokens into per-expert segments ----------------
__global__ __launch_bounds__(64) void k_scatter(const int* __restrict__ topi,
                                                const float* __restrict__ topp,
                                                const int* __restrict__ offs,
                                                int* __restrict__ cursor,
                                                int* __restrict__ rowmap,
                                                float* __restrict__ rowp,
                                                int* __restrict__ slotOf) {
  int t = blockIdx.x * blockDim.x + threadIdx.x;
  if (t >= T) return;
  #pragma unroll
  for (int s = 0; s < 2; ++s) {
    int e = topi[t * 2 + s];
    int pos = offs[e] + atomicAdd(&cursor[e], 1);
    rowmap[pos] = t;
    rowp[pos] = topp[t * 2 + s];
    slotOf[t * 2 + s] = pos;
  }
}

// ============ fused gate+up GEMM + SiLU*up, BK=64, XOR-swizzled LDS ============
// BM=128, BN=64 (x2 mats), 4 waves 2x2, wave tile 64x32 per matrix.
// LDS rows are 128 B = 8 x 16B slots; logical slot ls lives at phys ls^(row&7).
// Staging: linear LDS dest (global_load_lds), inverse-swizzled global source.
__global__ __launch_bounds__(256) void k_gateup(
    const bf16* __restrict__ A, const int* __restrict__ rowmap,
    const int* __restrict__ offs, const bf16* __restrict__ Bg,
    const bf16* __restrict__ Bu, bf16* __restrict__ outp, int Nd, int Kd) {
  __shared__ alignas(16) bf16 As[128 * 64];
  __shared__ alignas(16) bf16 Bgs[64 * 64];
  __shared__ alignas(16) bf16 Bus[64 * 64];
  const int z = blockIdx.z;
  const int r0 = offs[z], r1 = offs[z + 1];
  const int mbase = r0 + blockIdx.y * 128;
  if (mbase >= r1) return;
  const int n0 = blockIdx.x * 64;
  const int tid = threadIdx.x, wid = tid >> 6, lane = tid & 63;

  // staging geometry: issue i covers rows i*32 + (tid>>3), phys slot tid&7
  const int srow = tid >> 3;                    // 0..31 within issue
  const int ls = (tid & 7) ^ (srow & 7);        // logical slot this thread fetches
  const bf16* aSrc[4];
  #pragma unroll
  for (int i = 0; i < 4; ++i) {
    int row = i * 32 + srow;
    int g = mbase + row; if (g >= r1) g = r1 - 1;
    int s = rowmap ? rowmap[g] : g;
    aSrc[i] = A + (size_t)s * Kd + ls * 8;
  }
  const size_t bstride = (size_t)Nd * Kd;
  const bf16 *bgSrc[2], *buSrc[2];
  #pragma unroll
  for (int i = 0; i < 2; ++i) {
    int row = i * 32 + srow;
    size_t off = (size_t)z * bstride + (size_t)(n0 + row) * Kd + ls * 8;
    bgSrc[i] = Bg + off;
    buSrc[i] = Bu + off;
  }
  bf16* aDst[4]; bf16* bgDst[2]; bf16* buDst[2];
  #pragma unroll
  for (int i = 0; i < 4; ++i) aDst[i] = &As[i * 2048 + wid * 512];
  #pragma unroll
  for (int i = 0; i < 2; ++i) { bgDst[i] = &Bgs[i * 2048 + wid * 512];
                                buDst[i] = &Bus[i * 2048 + wid * 512]; }

  f32x4 zz = {0.f, 0.f, 0.f, 0.f};
  f32x4 accg[4][2], accu[4][2];
  #pragma unroll
  for (int m = 0; m < 4; ++m)
    #pragma unroll
    for (int n = 0; n < 2; ++n) { accg[m][n] = zz; accu[m][n] = zz; }

  const int wr = wid >> 1, wc = wid & 1;
  const int frow = lane & 15, x7 = frow & 7, khi = lane >> 4;

  for (int k0 = 0; k0 < Kd; k0 += 64) {
    #pragma unroll
    for (int i = 0; i < 4; ++i) gload_lds16(aSrc[i] + k0, aDst[i]);
    #pragma unroll
    for (int i = 0; i < 2; ++i) { gload_lds16(bgSrc[i] + k0, bgDst[i]);
                                  gload_lds16(buSrc[i] + k0, buDst[i]); }
    __syncthreads();
    #pragma unroll
    for (int s = 0; s < 2; ++s) {
      const int phys = ((4 * s + khi) ^ x7) * 8;
      bf16x8 af[4], bgf[2], buf2[2];
      #pragma unroll
      for (int m = 0; m < 4; ++m)
        af[m] = *reinterpret_cast<const bf16x8*>(&As[(wr * 64 + m * 16 + frow) * 64 + phys]);
      #pragma unroll
      for (int n = 0; n < 2; ++n) {
        bgf[n]  = *reinterpret_cast<const bf16x8*>(&Bgs[(wc * 32 + n * 16 + frow) * 64 + phys]);
        buf2[n] = *reinterpret_cast<const bf16x8*>(&Bus[(wc * 32 + n * 16 + frow) * 64 + phys]);
      }
      #pragma unroll
      for (int m = 0; m < 4; ++m)
        #pragma unroll
        for (int n = 0; n < 2; ++n) {
          accg[m][n] = __builtin_amdgcn_mfma_f32_16x16x32_bf16(af[m], bgf[n],  accg[m][n], 0, 0, 0);
          accu[m][n] = __builtin_amdgcn_mfma_f32_16x16x32_bf16(af[m], buf2[n], accu[m][n], 0, 0, 0);
        }
    }
    __syncthreads();
  }

  #pragma unroll
  for (int m = 0; m < 4; ++m)
    #pragma unroll
    for (int n = 0; n < 2; ++n)
      #pragma unroll
      for (int j = 0; j < 4; ++j) {
        int r = mbase + wr * 64 + m * 16 + (lane >> 4) * 4 + j;
        if (r < r1) {
          int c = n0 + wc * 32 + n * 16 + (lane & 15);
          float g = accg[m][n][j], u = accu[m][n][j];
          float sv = g / (1.f + __expf(-g));
          outp[(size_t)r * Nd + c] = (bf16)(sv * u);
        }
      }
}

// ============ fused down GEMM (experts + shared), split-K x2, f32 partials ============
// BM=128, BN=128, BK=64, 4 waves 2x2, wave tile 64x64. Same XOR-swizzled LDS.
// z in [0,16): expert e=z>>1, chunk=z&1 (K 2816 -> 2x1408)
// z in [16,18): shared, chunk=z-16      (K 1408 -> 2x704)
__global__ __launch_bounds__(256) void k_down(
    const bf16* __restrict__ act, const bf16* __restrict__ sact,
    const float* __restrict__ rowp, const int* __restrict__ offs,
    const bf16* __restrict__ WdT, const bf16* __restrict__ SdT,
    float* __restrict__ pd, float* __restrict__ ps) {
  __shared__ alignas(16) bf16 Asm[128 * 64];
  __shared__ alignas(16) bf16 Bsm[128 * 64];
  const int z = blockIdx.z;
  const bf16* A; const bf16* Bt; const float* scale; float* outp;
  int r0, r1, Kd, kbase, klen;
  if (z < 16) {
    int e = z >> 1, c = z & 1;
    A = act; Bt = WdT + (size_t)e * HD * IEXP; scale = rowp;
    outp = pd + (size_t)c * NSLOT * HD;
    r0 = offs[e]; r1 = offs[e + 1]; Kd = IEXP; klen = IEXP / 2; kbase = c * klen;
  } else {
    int c = z - 16;
    A = sact; Bt = SdT; scale = nullptr;
    outp = ps + (size_t)c * T * HD;
    r0 = 0; r1 = T; Kd = ISH; klen = ISH / 2; kbase = c * klen;
  }
  const int mbase = r0 + blockIdx.y * 128;
  if (mbase >= r1) return;
  const int n0 = blockIdx.x * 128;
  const int tid = threadIdx.x, wid = tid >> 6, lane = tid & 63;

  const int srow = tid >> 3;
  const int ls = (tid & 7) ^ (srow & 7);
  const bf16* aSrc[4]; const bf16* bSrc[4];
  #pragma unroll
  for (int i = 0; i < 4; ++i) {
    int row = i * 32 + srow;
    int g = mbase + row; if (g >= r1) g = r1 - 1;
    aSrc[i] = A + (size_t)g * Kd + kbase + ls * 8;
    bSrc[i] = Bt + (size_t)(n0 + row) * Kd + kbase + ls * 8;
  }
  bf16* aDst[4]; bf16* bDst[4];
  #pragma unroll
  for (int i = 0; i < 4; ++i) { aDst[i] = &Asm[i * 2048 + wid * 512];
                                bDst[i] = &Bsm[i * 2048 + wid * 512]; }

  f32x4 zz = {0.f, 0.f, 0.f, 0.f};
  f32x4 acc[4][4];
  #pragma unroll
  for (int m = 0; m < 4; ++m)
    #pragma unroll
    for (int n = 0; n < 4; ++n) acc[m][n] = zz;

  const int wr = wid >> 1, wc = wid & 1;
  const int frow = lane & 15, x7 = frow & 7, khi = lane >> 4;

  for (int k0 = 0; k0 < klen; k0 += 64) {
    #pragma unroll
    for (int i = 0; i < 4; ++i) { gload_lds16(aSrc[i] + k0, aDst[i]);
                                  gload_lds16(bSrc[i] + k0, bDst[i]); }
    __syncthreads();
    #pragma unroll
    for (int s = 0; s < 2; ++s) {
      const int phys = ((4 * s + khi) ^ x7) * 8;
      bf16x8 af[4], bfr[4];
      #pragma unroll
      for (int m = 0; m < 4; ++m)
        af[m] = *reinterpret_cast<const bf16x8*>(&Asm[(wr * 64 + m * 16 + frow) * 64 + phys]);
      #pragma unroll
      for (int n = 0; n < 4; ++n)
        bfr[n] = *reinterpret_cast<const bf16x8*>(&Bsm[(wc * 64 + n * 16 + frow) * 64 + phys]);
      #pragma unroll
      for (int m = 0; m < 4; ++m)
        #pragma unroll
        for (int n = 0; n < 4; ++n)
          acc[m][n] = __builtin_amdgcn_mfma_f32_16x16x32_bf16(af[m], bfr[n], acc[m][n], 0, 0, 0);
    }
    __syncthreads();
  }

  #pragma unroll
  for (int m = 0; m < 4; ++m)
    #pragma unroll
    for (int j = 0; j < 4; ++j) {
      int r = mbase + wr * 64 + m * 16 + (lane >> 4) * 4 + j;
      if (r < r1) {
        float sc = scale ? scale[r] : 1.f;
        #pragma unroll
        for (int n = 0; n < 4; ++n) {
          int c = n0 + wc * 64 + n * 16 + (lane & 15);
          outp[(size_t)r * HD + c] = sc * acc[m][n][j];
        }
      }
    }
}

// ---------------- final combine: 2 expert slots x 2 chunks + shared x 2 ----------------
__global__ __launch_bounds__(256) void k_combine(const float* __restrict__ pd,
                                                 const float* __restrict__ ps,
                                                 const int* __restrict__ slotOf,
                                                 float* __restrict__ outp) {
  int i = blockIdx.x * blockDim.x + threadIdx.x;  // over T*HD/4
  if (i >= T * HD / 4) return;
  int t = i >> 8;
  int off = (i & 255) * 4;
  int s0 = slotOf[t * 2], s1 = slotOf[t * 2 + 1];
  const float* pd1 = pd + (size_t)NSLOT * HD;
  const float* ps1 = ps + (size_t)T * HD;
  float4 a0 = *reinterpret_cast<const float4*>(pd  + (size_t)s0 * HD + off);
  float4 a1 = *reinterpret_cast<const float4*>(pd1 + (size_t)s0 * HD + off);
  float4 b0 = *reinterpret_cast<const float4*>(pd  + (size_t)s1 * HD + off);
  float4 b1 = *reinterpret_cast<const float4*>(pd1 + (size_t)s1 * HD + off);
  float4 c0 = *reinterpret_cast<const float4*>(ps  + (size_t)i * 4);
  float4 c1 = *reinterpret_cast<const float4*>(ps1 + (size_t)i * 4);
  float4 o;
  o.x = a0.x + a1.x + b0.x + b1.x + c0.x + c1.x;
  o.y = a0.y + a1.y + b0.y + b1.y + c0.y + c1.y;
  o.z = a0.z + a1.z + b0.z + b1.z + c0.z + c1.z;
  o.w = a0.w + a1.w + b0.w + b1.w + c0.w + c1.w;
  *reinterpret_cast<float4*>(outp + (size_t)i * 4) = o;
}

static inline size_t algn(size_t x) { return (x + 255) & ~(size_t)255; }

extern "C" void kernel_launch(void* const* d_in, const int* in_sizes, int n_in,
                              void* d_out, int out_size, void* d_ws, size_t ws_size,
                              hipStream_t stream) {
  const float* x  = (const float*)d_in[0];
  const float* gw = (const float*)d_in[1];
  const float* Wg = (const float*)d_in[2];
  const float* Wu = (const float*)d_in[3];
  const float* Wd = (const float*)d_in[4];
  const float* Sg = (const float*)d_in[5];
  const float* Su = (const float*)d_in[6];
  const float* Sd = (const float*)d_in[7];
  float* out = (float*)d_out;

  char* p = (char*)d_ws;
  auto carve = [&](size_t bytes) -> char* { char* r = p; p += algn(bytes); return r; };
  bf16* xb   = (bf16*)carve((size_t)T * HD * 2);
  bf16* WgT  = (bf16*)carve((size_t)NE * IEXP * HD * 2);
  bf16* WuT  = (bf16*)carve((size_t)NE * IEXP * HD * 2);
  bf16* WdT  = (bf16*)carve((size_t)NE * HD * IEXP * 2);
  bf16* SgT  = (bf16*)carve((size_t)ISH * HD * 2);
  bf16* SuT  = (bf16*)carve((size_t)ISH * HD * 2);
  bf16* SdT  = (bf16*)carve((size_t)HD * ISH * 2);
  bf16* act  = (bf16*)carve((size_t)NSLOT * IEXP * 2);
  bf16* sact = (bf16*)carve((size_t)T * ISH * 2);
  float* pd  = (float*)carve((size_t)2 * NSLOT * HD * 4);
  float* ps  = (float*)carve((size_t)2 * T * HD * 4);
  int*   topi   = (int*)carve(T * 2 * 4);
  float* topp   = (float*)carve(T * 2 * 4);
  int*   rowmap = (int*)carve(NSLOT * 4);
  float* rowp   = (float*)carve(NSLOT * 4);
  int*   slotOf = (int*)carve(T * 2 * 4);
  int*   counts = (int*)carve(NE * 4);
  int*   offs   = (int*)carve((NE + 1) * 4);
  int*   cursor = (int*)carve(NE * 4);
  int*   soffs  = (int*)carve(2 * 4);

  hipMemsetAsync(counts, 0, NE * sizeof(int), stream);

  k_convert_x<<<T * HD / 4 / 256, 256, 0, stream>>>(x, xb, T * HD / 4);

  // weights: [K][N] f32 -> [N][K] bf16
  k_transpose64<<<dim3(IEXP / 64, HD / 64, NE), 256, 0, stream>>>(Wg, WgT, HD, IEXP);
  k_transpose64<<<dim3(IEXP / 64, HD / 64, NE), 256, 0, stream>>>(Wu, WuT, HD, IEXP);
  k_transpose64<<<dim3(HD / 64, IEXP / 64, NE), 256, 0, stream>>>(Wd, WdT, IEXP, HD);
  k_transpose64<<<dim3(ISH / 64, HD / 64, 1), 256, 0, stream>>>(Sg, SgT, HD, ISH);
  k_transpose64<<<dim3(ISH / 64, HD / 64, 1), 256, 0, stream>>>(Su, SuT, HD, ISH);
  k_transpose64<<<dim3(HD / 64, ISH / 64, 1), 256, 0, stream>>>(Sd, SdT, ISH, HD);

  k_router<<<T, 64, 0, stream>>>(x, gw, topi, topp, counts);
  k_scan<<<1, 64, 0, stream>>>(counts, offs, cursor, soffs);
  k_scatter<<<T / 64, 64, 0, stream>>>(topi, topp, offs, cursor, rowmap, rowp, slotOf);

  // expert gate+up (rows gathered via rowmap); max 2048 rows/expert -> 16 tiles
  k_gateup<<<dim3(IEXP / 64, 16, NE), 256, 0, stream>>>(xb, rowmap, offs, WgT, WuT,
                                                        act, IEXP, HD);
  // shared gate+up over all tokens
  k_gateup<<<dim3(ISH / 64, T / 128, 1), 256, 0, stream>>>(xb, nullptr, soffs, SgT, SuT,
                                                           sact, ISH, HD);
  // fused expert+shared down, split-K x2
  k_down<<<dim3(HD / 128, 16, 18), 256, 0, stream>>>(act, sact, rowp, offs, WdT, SdT,
                                                     pd, ps);

  k_combine<<<T * HD / 4 / 256, 256, 0, stream>>>(pd, ps, slotOf, out);

  (void)in_sizes; (void)n_in; (void)out_size; (void)ws_size;
}